// Round 3
// baseline (152.673 us; speedup 1.0000x reference)
//
#include <hip/hip_runtime.h>
#include <math.h>

#define CB 8      // q,k channels
#define CC 64     // C
#define HH 256
#define WW 256

// Lane map: w = t&63 (column within 64-col tile, consecutive lanes = consecutive
// columns -> perfectly coalesced global access), r = t>>6 (row: wave id, 4 waves).
// Horizontal attention mixes rows -> cross-wave via LDS.
// Vertical attention mixes columns within 4-col blocks -> LDS broadcast reads.
//
// __launch_bounds__(256, 2): min 2 waves/EU -> VGPR cap 256, so xr[64] stays
// in registers (round-2 showed the default cap of 64 VGPRs spilled xr to
// scratch, costing +134 MB of HBM writes and latency-binding the kernel).
__global__ __launch_bounds__(256, 2) void area_attn_kernel(
    const float* __restrict__ x,
    const float* __restrict__ Wq, const float* __restrict__ bq,
    const float* __restrict__ Wk, const float* __restrict__ bk,
    const float* __restrict__ Wv, const float* __restrict__ bv,
    const float* __restrict__ gamma,
    float* __restrict__ out)
{
    __shared__ float  k_lds[8 * 4 * 64];            // [c][row][w]   8 KB
    __shared__ float4 ah4[4 * 64];                  // [row][w]      4 KB
    __shared__ float4 av4[4 * 64];                  // [row][w]      4 KB
    __shared__ float  v_lds[2 * 8 * 4 * 64];        // [buf][cc][row][w] 16 KB

    const int t  = threadIdx.x;
    const int w  = t & 63;        // column within tile
    const int r  = t >> 6;        // row within 4-row block (= wave id)
    const int jc = w & 3;         // my column index within 4-col block
    const int wb = w & ~3;        // base of my 4-col block

    const int wg = blockIdx.x * 64 + w;
    const int h  = blockIdx.y * 4 + r;
    const int b  = blockIdx.z;

    const size_t HW  = (size_t)HH * WW;
    const size_t pix = (size_t)b * CC * HW + (size_t)h * WW + wg;

    // ---- load my pixel's 64 channels (coalesced: lanes = consecutive w) ----
    float xr[CC];
#pragma unroll
    for (int c = 0; c < CC; ++c) xr[c] = x[pix + (size_t)c * HW];

    // ---- q,k conv (8 ch each) ----
    float vq[CB], vk[CB];
#pragma unroll
    for (int o = 0; o < CB; ++o) { vq[o] = bq[o]; vk[o] = bk[o]; }
#pragma unroll
    for (int c = 0; c < CC; ++c) {
        const float xv = xr[c];
#pragma unroll
        for (int o = 0; o < CB; ++o) {
            vq[o] = fmaf(xv, Wq[o * CC + c], vq[o]);
            vk[o] = fmaf(xv, Wk[o * CC + c], vk[o]);
        }
    }

    // publish k: k_lds[c][r][w]
#pragma unroll
    for (int c = 0; c < CB; ++c) k_lds[c * 256 + r * 64 + w] = vk[c];
    __syncthreads();

    // ---- horizontal scores: I am query row r; S[j] = q(me) . k(row j, col w) ----
    {
        float S[4];
#pragma unroll
        for (int j = 0; j < 4; ++j) {
            float s = 0.f;
#pragma unroll
            for (int c = 0; c < CB; ++c)
                s = fmaf(vq[c], k_lds[c * 256 + j * 64 + w], s);
            S[j] = s;
        }
        float m  = fmaxf(fmaxf(S[0], S[1]), fmaxf(S[2], S[3]));
        float e0 = __expf(S[0] - m), e1 = __expf(S[1] - m);
        float e2 = __expf(S[2] - m), e3 = __expf(S[3] - m);
        float inv = 1.f / (e0 + e1 + e2 + e3);
        ah4[r * 64 + w] = make_float4(e0 * inv, e1 * inv, e2 * inv, e3 * inv);
    }

    // ---- vertical scores: I am query col jc; S[j] = q(me) . k(row r, col wb|j) ----
    {
        float S[4];
#pragma unroll
        for (int j = 0; j < 4; ++j) {
            float s = 0.f;
#pragma unroll
            for (int c = 0; c < CB; ++c)
                s = fmaf(vq[c], k_lds[c * 256 + r * 64 + (wb | j)], s);
            S[j] = s;
        }
        float m  = fmaxf(fmaxf(S[0], S[1]), fmaxf(S[2], S[3]));
        float e0 = __expf(S[0] - m), e1 = __expf(S[1] - m);
        float e2 = __expf(S[2] - m), e3 = __expf(S[3] - m);
        float inv = 1.f / (e0 + e1 + e2 + e3);
        av4[r * 64 + w] = make_float4(e0 * inv, e1 * inv, e2 * inv, e3 * inv);
    }
    __syncthreads();

    // ---- gather the A-columns I need as output index ----
    // h: out col j = r  -> need A_h[i][r] from row-i threads (same w)
    // v: out col j = jc -> need A_v[i][jc] from threads at col wb|i (same row)
    float ahc[4], avc[4];
#pragma unroll
    for (int i = 0; i < 4; ++i) {
        ahc[i] = ((const float*)&ah4[i * 64 + w])[r];
        avc[i] = ((const float*)&av4[r * 64 + (wb | i)])[jc];
    }

    const float g = gamma[0];

    // ---- v conv + PV + epilogue, chunked 8 channels at a time (double-buffered) ----
    for (int cb = 0; cb < 8; ++cb) {
        const int p = (cb & 1) * 2048;

        // conv: 8 v-channels for my pixel
        float v8[8];
#pragma unroll
        for (int j = 0; j < 8; ++j) {
            const int o = cb * 8 + j;
            float s = bv[o];
#pragma unroll
            for (int c = 0; c < CC; ++c)
                s = fmaf(xr[c], Wv[o * CC + c], s);
            v8[j] = s;
        }

        // publish chunk: v_lds[p][cc][row][w]
#pragma unroll
        for (int j = 0; j < 8; ++j) v_lds[p + j * 256 + r * 64 + w] = v8[j];
        __syncthreads();

        // PV: out[c] = sum_i A_h[i][r] * v(row i, col w)
        //            + sum_i A_v[i][jc] * v(row r, col wb|i)
        float o8[8] = {0.f, 0.f, 0.f, 0.f, 0.f, 0.f, 0.f, 0.f};
#pragma unroll
        for (int i = 0; i < 4; ++i) {
#pragma unroll
            for (int j = 0; j < 8; ++j) {
                o8[j] = fmaf(ahc[i], v_lds[p + j * 256 + i * 64 + w], o8[j]);
                o8[j] = fmaf(avc[i], v_lds[p + j * 256 + r * 64 + (wb | i)], o8[j]);
            }
        }

        // epilogue: out = gamma*(h+v) + x   (coalesced stores)
#pragma unroll
        for (int j = 0; j < 8; ++j) {
            const int o = cb * 8 + j;
            out[pix + (size_t)o * HW] = fmaf(g, o8[j], xr[o]);
        }
    }
}

extern "C" void kernel_launch(void* const* d_in, const int* in_sizes, int n_in,
                              void* d_out, int out_size, void* d_ws, size_t ws_size,
                              hipStream_t stream) {
    const float* x     = (const float*)d_in[0];
    const float* Wq    = (const float*)d_in[1];
    const float* bq    = (const float*)d_in[2];
    const float* Wk    = (const float*)d_in[3];
    const float* bk    = (const float*)d_in[4];
    const float* Wv    = (const float*)d_in[5];
    const float* bv    = (const float*)d_in[6];
    const float* gamma = (const float*)d_in[7];
    float* out = (float*)d_out;

    dim3 grid(WW / 64, HH / 4, 8);   // (4, 64, 8)
    area_attn_kernel<<<grid, 256, 0, stream>>>(x, Wq, bq, Wk, bk, Wv, bv, gamma, out);
}

// Round 4
// 121.832 us; speedup vs baseline: 1.2531x; 1.2531x over previous
//
#include <hip/hip_runtime.h>
#include <math.h>

#define CB 8      // q,k channels
#define CC 64     // C
#define HH 256
#define WW 256

// Lane map: w = t&63 (column within 64-col tile, consecutive lanes = consecutive
// columns -> coalesced global access), r = t>>6 (row = wave id, 4 waves).
// Horizontal attention mixes rows -> cross-wave via LDS.
// Vertical attention mixes columns within 4-col blocks -> LDS broadcast reads.
//
// CRITICAL (round-3 lesson, rule #20): the chunk loop MUST be fully unrolled.
// A runtime-indexed access xr[cb*8+j] forces xr[64] into scratch (localMem),
// which showed up as exactly +134 MB of HBM WRITE (256 B/thread spill) and
// latency-bound execution at 204 us. With the unroll every index is static
// and xr stays in VGPRs. __launch_bounds__(256,2) gives the allocator room.
__global__ __launch_bounds__(256, 2) void area_attn_kernel(
    const float* __restrict__ x,
    const float* __restrict__ Wq, const float* __restrict__ bq,
    const float* __restrict__ Wk, const float* __restrict__ bk,
    const float* __restrict__ Wv, const float* __restrict__ bv,
    const float* __restrict__ gamma,
    float* __restrict__ out)
{
    __shared__ float  k_lds[8 * 4 * 64];            // [c][row][w]   8 KB
    __shared__ float4 ah4[4 * 64];                  // [row][w]      4 KB
    __shared__ float4 av4[4 * 64];                  // [row][w]      4 KB
    __shared__ float  v_lds[2 * 8 * 4 * 64];        // [buf][cc][row][w] 16 KB

    const int t  = threadIdx.x;
    const int w  = t & 63;        // column within tile
    const int r  = t >> 6;        // row within 4-row block (= wave id)
    const int jc = w & 3;         // my column index within 4-col block
    const int wb = w & ~3;        // base of my 4-col block

    const int wg = blockIdx.x * 64 + w;
    const int h  = blockIdx.y * 4 + r;
    const int b  = blockIdx.z;

    const size_t HW  = (size_t)HH * WW;
    const size_t pix = (size_t)b * CC * HW + (size_t)h * WW + wg;

    // ---- load my pixel's 64 channels (coalesced: lanes = consecutive w) ----
    float xr[CC];
#pragma unroll
    for (int c = 0; c < CC; ++c) xr[c] = x[pix + (size_t)c * HW];

    // ---- q,k conv (8 ch each) ----
    float vq[CB], vk[CB];
#pragma unroll
    for (int o = 0; o < CB; ++o) { vq[o] = bq[o]; vk[o] = bk[o]; }
#pragma unroll
    for (int c = 0; c < CC; ++c) {
        const float xv = xr[c];
#pragma unroll
        for (int o = 0; o < CB; ++o) {
            vq[o] = fmaf(xv, Wq[o * CC + c], vq[o]);
            vk[o] = fmaf(xv, Wk[o * CC + c], vk[o]);
        }
    }

    // publish k: k_lds[c][r][w]
#pragma unroll
    for (int c = 0; c < CB; ++c) k_lds[c * 256 + r * 64 + w] = vk[c];
    __syncthreads();

    // ---- horizontal scores: I am query row r; S[j] = q(me) . k(row j, col w) ----
    {
        float S[4];
#pragma unroll
        for (int j = 0; j < 4; ++j) {
            float s = 0.f;
#pragma unroll
            for (int c = 0; c < CB; ++c)
                s = fmaf(vq[c], k_lds[c * 256 + j * 64 + w], s);
            S[j] = s;
        }
        float m  = fmaxf(fmaxf(S[0], S[1]), fmaxf(S[2], S[3]));
        float e0 = __expf(S[0] - m), e1 = __expf(S[1] - m);
        float e2 = __expf(S[2] - m), e3 = __expf(S[3] - m);
        float inv = 1.f / (e0 + e1 + e2 + e3);
        ah4[r * 64 + w] = make_float4(e0 * inv, e1 * inv, e2 * inv, e3 * inv);
    }

    // ---- vertical scores: I am query col jc; S[j] = q(me) . k(row r, col wb|j) ----
    {
        float S[4];
#pragma unroll
        for (int j = 0; j < 4; ++j) {
            float s = 0.f;
#pragma unroll
            for (int c = 0; c < CB; ++c)
                s = fmaf(vq[c], k_lds[c * 256 + r * 64 + (wb | j)], s);
            S[j] = s;
        }
        float m  = fmaxf(fmaxf(S[0], S[1]), fmaxf(S[2], S[3]));
        float e0 = __expf(S[0] - m), e1 = __expf(S[1] - m);
        float e2 = __expf(S[2] - m), e3 = __expf(S[3] - m);
        float inv = 1.f / (e0 + e1 + e2 + e3);
        av4[r * 64 + w] = make_float4(e0 * inv, e1 * inv, e2 * inv, e3 * inv);
    }
    __syncthreads();

    // ---- gather the A-columns I need as output index ----
    float ahc[4], avc[4];
#pragma unroll
    for (int i = 0; i < 4; ++i) {
        ahc[i] = ((const float*)&ah4[i * 64 + w])[r];
        avc[i] = ((const float*)&av4[r * 64 + (wb | i)])[jc];
    }

    const float g = gamma[0];

    // ---- v conv + PV + epilogue, 8 channels/chunk, FULLY UNROLLED ----
#pragma unroll
    for (int cb = 0; cb < 8; ++cb) {
        const int p = (cb & 1) * 2048;

        // conv: 8 v-channels for my pixel
        float v8[8];
#pragma unroll
        for (int j = 0; j < 8; ++j) {
            const int o = cb * 8 + j;
            float s = bv[o];
#pragma unroll
            for (int c = 0; c < CC; ++c)
                s = fmaf(xr[c], Wv[o * CC + c], s);
            v8[j] = s;
        }

        // publish chunk: v_lds[p][cc][row][w]
#pragma unroll
        for (int j = 0; j < 8; ++j) v_lds[p + j * 256 + r * 64 + w] = v8[j];
        __syncthreads();

        // PV: out[c] = sum_i A_h[i][r] * v(row i, col w)
        //            + sum_i A_v[i][jc] * v(row r, col wb|i)
        float o8[8] = {0.f, 0.f, 0.f, 0.f, 0.f, 0.f, 0.f, 0.f};
#pragma unroll
        for (int i = 0; i < 4; ++i) {
#pragma unroll
            for (int j = 0; j < 8; ++j) {
                o8[j] = fmaf(ahc[i], v_lds[p + j * 256 + i * 64 + w], o8[j]);
                o8[j] = fmaf(avc[i], v_lds[p + j * 256 + r * 64 + (wb | i)], o8[j]);
            }
        }

        // epilogue: out = gamma*(h+v) + x   (coalesced stores; xr index static)
#pragma unroll
        for (int j = 0; j < 8; ++j) {
            const int o = cb * 8 + j;
            out[pix + (size_t)o * HW] = fmaf(g, o8[j], xr[o]);
        }
    }
}

extern "C" void kernel_launch(void* const* d_in, const int* in_sizes, int n_in,
                              void* d_out, int out_size, void* d_ws, size_t ws_size,
                              hipStream_t stream) {
    const float* x     = (const float*)d_in[0];
    const float* Wq    = (const float*)d_in[1];
    const float* bq    = (const float*)d_in[2];
    const float* Wk    = (const float*)d_in[3];
    const float* bk    = (const float*)d_in[4];
    const float* Wv    = (const float*)d_in[5];
    const float* bv    = (const float*)d_in[6];
    const float* gamma = (const float*)d_in[7];
    float* out = (float*)d_out;

    dim3 grid(WW / 64, HH / 4, 8);   // (4, 64, 8)
    area_attn_kernel<<<grid, 256, 0, stream>>>(x, Wq, bq, Wk, bk, Wv, bv, gamma, out);
}